// Round 8
// baseline (137.147 us; speedup 1.0000x reference)
//
#include <hip/hip_runtime.h>
#include <hip/hip_bf16.h>

// Problem constants
#define BB 16
#define SS 1024
#define DD 384
#define HH 6
#define KK 9
#define KH 54      // K*H
#define OUTD 384
#define NKT 12     // K-steps: 384/32
#define VLD 392    // LDS leading dim (bf16): 784 B/row -> 4-bank shift/row, <=2-way (free)

typedef __attribute__((ext_vector_type(4))) float floatx4;
typedef __attribute__((ext_vector_type(8))) __bf16 bf16x8;
typedef __attribute__((ext_vector_type(4))) __bf16 bf16x4;

// ---------------------------------------------------------------------------
// Kernel 0: cast + swizzle weights into MFMA B-fragment order.
// WkT: 4 ntiles (54 rows zero-padded to 64) x 12 ksteps x 64 lanes x 8 bf16.
// WpT: 24 ntiles x 12 ksteps x 64 lanes x 8 bf16.
// Fragment: lane = n_in_tile(0..15) + 16*k_quad; elems = 8 consecutive k.
// Every MFMA B-load is ONE lane-contiguous 1-KB transaction (L2-resident).
// ---------------------------------------------------------------------------
__global__ __launch_bounds__(256) void cast_kernel(const float* __restrict__ Wk,
                                                   const float* __restrict__ Wp,
                                                   __bf16* __restrict__ WkT,
                                                   __bf16* __restrict__ WpT) {
    int i = blockIdx.x * 256 + threadIdx.x;
    if (i < 4 * NKT * 64 * 8) {                    // 24576 elems of WkT
        int e = i & 7, lane = (i >> 3) & 63, t = i >> 9;
        int kstep = t % NKT, ntile = t / NKT;
        int row = ntile * 16 + (lane & 15);
        int col = kstep * 32 + ((lane >> 4) << 3) + e;
        WkT[i] = (row < KH) ? (__bf16)Wk[row * DD + col] : (__bf16)0.0f;
    } else if (i < 24576 + 24 * NKT * 64 * 8) {    // 147456 elems of WpT
        int j = i - 24576;
        int e = j & 7, lane = (j >> 3) & 63, t = j >> 9;
        int kstep = t % NKT, ntile = t / NKT;
        int row = ntile * 16 + (lane & 15);
        int col = kstep * 32 + ((lane >> 4) << 3) + e;
        WpT[j] = (__bf16)Wp[row * DD + col];
    }
}

// ---------------------------------------------------------------------------
// Kernel 1 (stage1): logits=(q*ks)@Wk^T+bk -> softmax(9) -> 9-tap conv.
// Block = 16 seq rows, grid 1024, 3 barriers. Conv output written DIRECTLY
// in MFMA A-fragment order (coalesced bf16x8 stores) to Aws:
//   Aws[((mtile*12 + s)*64 + lane)*8], lane = m(0..15) + 16*k_quad.
// LDS = 12544 (qk) + 18816 (v) + 3584 (dk) + 4224 (lg) = 39168 -> 4 blk/CU.
// ---------------------------------------------------------------------------
__global__ __launch_bounds__(256, 4) void stage1_kernel(const float* __restrict__ q,
                                                        const float* __restrict__ ks,
                                                        const float* __restrict__ v,
                                                        const __bf16* __restrict__ WkT,
                                                        const float* __restrict__ bk,
                                                        __bf16* __restrict__ Aws) {
    __shared__ __bf16 qkS[16 * VLD];   // 12544 B
    __shared__ __bf16 vS[24 * VLD];    // 18816 B: window rows s0-4 .. s0+19
    __shared__ float  dkS[16 * 56];    //  3584 B
    __shared__ float  lgS[16 * 66];    //  4224 B

    const int tid  = threadIdx.x;
    const int wave = tid >> 6;
    const int lane = tid & 63;
    const int m0   = blockIdx.x * 16;
    const int b    = blockIdx.x >> 6;                  // 64 blocks per batch
    const int s0   = (blockIdx.x & 63) * 16;
    const int fr   = lane & 15;
    const int fk   = (lane >> 4) * 8;
    const int col_in = lane & 15;
    const int rgrp   = (lane >> 4) * 4;

    // ---- P0: stage qk (16x384) and v window (24x384), all loads up front ----
    {
        const float* qb = q  + (size_t)m0 * DD;
        const float* kb = ks + (size_t)m0 * DD;
#pragma unroll
        for (int it = 0; it < 6; ++it) {
            int c = tid + it * 256;                    // float4-chunks
            int row = c / 96, col = (c % 96) * 4;
            floatx4 qv = *reinterpret_cast<const floatx4*>(qb + (size_t)row * DD + col);
            floatx4 kv = *reinterpret_cast<const floatx4*>(kb + (size_t)row * DD + col);
            floatx4 pr = qv * kv;
            bf16x4 pk = { (__bf16)pr.x, (__bf16)pr.y, (__bf16)pr.z, (__bf16)pr.w };
            *reinterpret_cast<bf16x4*>(&qkS[row * VLD + col]) = pk;
        }
        const float* vb = v + (size_t)b * SS * DD;
        if (s0 != 0 && s0 != SS - 16) {
#pragma unroll
            for (int it = 0; it < 9; ++it) {
                int c = tid + it * 256;
                int row = c / 96, col = (c % 96) * 4;
                floatx4 val = *reinterpret_cast<const floatx4*>(
                    vb + (size_t)(s0 + row - 4) * DD + col);
                bf16x4 vk = { (__bf16)val.x, (__bf16)val.y, (__bf16)val.z, (__bf16)val.w };
                *reinterpret_cast<bf16x4*>(&vS[row * VLD + col]) = vk;
            }
        } else {
#pragma unroll
            for (int it = 0; it < 9; ++it) {
                int c = tid + it * 256;
                int row = c / 96, col = (c % 96) * 4;
                int r = s0 + row - 4;
                floatx4 val = {};
                if (r >= 0 && r < SS)
                    val = *reinterpret_cast<const floatx4*>(vb + (size_t)r * DD + col);
                bf16x4 vk = { (__bf16)val.x, (__bf16)val.y, (__bf16)val.z, (__bf16)val.w };
                *reinterpret_cast<bf16x4*>(&vS[row * VLD + col]) = vk;
            }
        }
    }
    __syncthreads();   // B1

    // ---- P1: logits MFMA. wave = ntile (full K, WkT read once/block) ----
    {
        floatx4 acc = {};
#pragma unroll
        for (int s = 0; s < NKT; ++s) {
            bf16x8 af = *reinterpret_cast<const bf16x8*>(&qkS[fr * VLD + s * 32 + fk]);
            bf16x8 bf = *reinterpret_cast<const bf16x8*>(
                WkT + (((wave * NKT + s) * 64 + lane) << 3));
            acc = __builtin_amdgcn_mfma_f32_16x16x32_bf16(af, bf, acc, 0, 0, 0);
        }
        // C/D layout: col = lane&15, row = (lane>>4)*4 + reg
#pragma unroll
        for (int r = 0; r < 4; ++r)
            lgS[(rgrp + r) * 66 + wave * 16 + col_in] = acc[r];
    }
    __syncthreads();   // B2

    // ---- P2: softmax over 9 taps (96 tasks) -> dkS ----
    if (tid < 16 * HH) {
        int row = tid / HH, h = tid % HH;
        float lg[KK];
        float mx = -1e30f;
#pragma unroll
        for (int k = 0; k < KK; ++k) {
            float s = lgS[row * 66 + h * KK + k] + bk[h * KK + k];
            lg[k] = s;
            mx = fmaxf(mx, s);
        }
        float sum = 0.0f;
#pragma unroll
        for (int k = 0; k < KK; ++k) { lg[k] = __expf(lg[k] - mx); sum += lg[k]; }
        float inv = 1.0f / sum;
#pragma unroll
        for (int k = 0; k < KK; ++k) dkS[row * 56 + h * KK + k] = lg[k] * inv;
    }
    __syncthreads();   // B3

    // ---- P3: 9-tap conv computed in A-FRAGMENT order; coalesced 16B stores ----
    // task p in [0,768): s = p>>6, ln = p&63, row = ln&15, d0 = s*32+(ln>>4)*8
    __bf16* ab = Aws + ((size_t)blockIdx.x * NKT * 64) * 8;
#pragma unroll
    for (int it = 0; it < 3; ++it) {
        int p = tid + it * 256;
        int s  = p >> 6, ln = p & 63;
        int row = ln & 15, d0 = s * 32 + ((ln >> 4) << 3);
        int h = d0 >> 6;
        const float* dkr = &dkS[row * 56 + h * KK];
        float a[8] = {};
#pragma unroll
        for (int k = 0; k < KK; ++k) {
            bf16x8 w = *reinterpret_cast<const bf16x8*>(&vS[(row + k) * VLD + d0]);
            float dv = dkr[k];
#pragma unroll
            for (int e = 0; e < 8; ++e) a[e] += (float)w[e] * dv;
        }
        bf16x8 o;
#pragma unroll
        for (int e = 0; e < 8; ++e) o[e] = (__bf16)a[e];
        *reinterpret_cast<bf16x8*>(&ab[(size_t)(s * 64 + ln) * 8]) = o;
    }
}

// ---------------------------------------------------------------------------
// Kernel 2 (stage2): C = A @ Wp^T + bp. ZERO barriers, ZERO LDS.
// wave = (mtile, col-quarter): 4096 waves, grid 1024 -> 16 streaming waves/CU.
// A-frags and WpT-frags are both 1-KB lane-contiguous loads.
// ---------------------------------------------------------------------------
__global__ __launch_bounds__(256) void stage2_kernel(const __bf16* __restrict__ Aws,
                                                     const __bf16* __restrict__ WpT,
                                                     const float* __restrict__ bp,
                                                     float* __restrict__ out) {
    const int tid   = threadIdx.x;
    const int wave  = tid >> 6;
    const int lane  = tid & 63;
    const int w     = blockIdx.x * 4 + wave;   // 0..4095
    const int mtile = w >> 2;
    const int colq  = w & 3;
    const int col_in = lane & 15;
    const int rgrp   = (lane >> 4) * 4;

    floatx4 acc[6] = {};
#pragma unroll
    for (int s = 0; s < NKT; ++s) {
        bf16x8 af = *reinterpret_cast<const bf16x8*>(
            Aws + (((size_t)(mtile * NKT + s) * 64 + lane) << 3));
#pragma unroll
        for (int j = 0; j < 6; ++j) {
            bf16x8 bf = *reinterpret_cast<const bf16x8*>(
                WpT + ((((colq * 6 + j) * NKT + s) * 64 + lane) << 3));
            acc[j] = __builtin_amdgcn_mfma_f32_16x16x32_bf16(af, bf, acc[j], 0, 0, 0);
        }
    }

    float* ob = out + (size_t)mtile * 16 * OUTD;
#pragma unroll
    for (int j = 0; j < 6; ++j) {
        int col = (colq * 6 + j) * 16 + col_in;
        float bv = bp[col];
#pragma unroll
        for (int r = 0; r < 4; ++r)
            ob[(size_t)(rgrp + r) * OUTD + col] = acc[j][r] + bv;
    }
}

// ---------------------------------------------------------------------------
extern "C" void kernel_launch(void* const* d_in, const int* in_sizes, int n_in,
                              void* d_out, int out_size, void* d_ws, size_t ws_size,
                              hipStream_t stream) {
    const float* q  = (const float*)d_in[0];
    const float* ks = (const float*)d_in[1];
    const float* v  = (const float*)d_in[2];
    const float* Wk = (const float*)d_in[3];
    const float* bk = (const float*)d_in[4];
    const float* Wp = (const float*)d_in[5];
    const float* bp = (const float*)d_in[6];
    float* out = (float*)d_out;

    // ws layout: WkT bf16 49152 B | WpT bf16 294912 B | Aws bf16 12582912 B
    __bf16* WkT = (__bf16*)d_ws;
    __bf16* WpT = (__bf16*)((char*)d_ws + 49152);
    __bf16* Aws = (__bf16*)((char*)d_ws + 49152 + 294912);

    cast_kernel<<<(24576 + 147456 + 255) / 256, 256, 0, stream>>>(Wk, Wp, WkT, WpT);
    stage1_kernel<<<(BB * SS) / 16, 256, 0, stream>>>(q, ks, v, WkT, bk, Aws);
    stage2_kernel<<<(BB * SS) / 16, 256, 0, stream>>>(Aws, WpT, bp, out);
}